// Round 7
// baseline (172.502 us; speedup 1.0000x reference)
//
#include <hip/hip_runtime.h>
#include <hip/hip_bf16.h>

// QNet: out[i] = w2 . relu( concat(embed[i], graph_embed[rep[i]]) @ w1^T + b1 ) + b2
// Split: pre = embed @ W1a^T (bf16 MFMA, K=64) + Gb[rep[i]] (fp32, MFMA C-init),
// Gb[b][n] = b1[n] + sum_k graph_embed[b][k] * w1[n][64+k]  (separate tiny kernel).
//
// Main kernel: 2048 blocks x 2 waves (hidden-split, 64 each). 6-slot LDS ring,
// stage-ahead 5 -> ~96KB reads in flight per CU at the wait points (6 blocks/CU).
// rep: per-block uint8 delta table in LDS (filled once); Gb rows COPIED to LDS
// once per block -> steady-state phases contain NO compiler-tracked global loads.
// global_load_lds staging from k-major pre-swizzled GLOBAL source (LDS linear),
// raw s_barrier + per-wave counted vmcnt, double-buffered LDS dot exchange.

#define D_LAT 64
#define H_HID 128
#define RING  6
#define TPB   64     // tiles per block

typedef short bf16x8 __attribute__((ext_vector_type(8)));
typedef float f32x4  __attribute__((ext_vector_type(4)));
typedef __attribute__((address_space(3))) float lds_f;

#define MFMA16 __builtin_amdgcn_mfma_f32_16x16x32_bf16

static __device__ inline short f2s(float f) {
    __bf16 h = (__bf16)f;
    return __builtin_bit_cast(short, h);
}
static __device__ inline bf16x8 pack8(f32x4 a, f32x4 b) {
    bf16x8 r;
    r[0] = f2s(a[0]); r[1] = f2s(a[1]); r[2] = f2s(a[2]); r[3] = f2s(a[3]);
    r[4] = f2s(b[0]); r[5] = f2s(b[1]); r[6] = f2s(b[2]); r[7] = f2s(b[3]);
    return r;
}
static __device__ inline void gll16(const float* g, float* l) {
    __builtin_amdgcn_global_load_lds((const __attribute__((address_space(1))) void*)g,
                                     (__attribute__((address_space(3))) void*)l, 16, 0, 0);
}

// Gb[b][n] = b1[n] + sum_{k<64} graph_embed[b][k] * w1[n][64+k]
__global__ void gb_kernel(const float* __restrict__ ge, const float* __restrict__ w1,
                          const float* __restrict__ b1, float* __restrict__ gb) {
    __shared__ float s[D_LAT];
    const int b = blockIdx.x, n = threadIdx.x;
    if (threadIdx.x < D_LAT) s[threadIdx.x] = ge[b * D_LAT + threadIdx.x];
    __syncthreads();
    float acc = b1[n];
    const float* wr = w1 + n * (2 * D_LAT) + D_LAT;
    #pragma unroll
    for (int k = 0; k < D_LAT; ++k) acc += s[k] * wr[k];
    gb[b * H_HID + n] = acc;
}

__global__ __launch_bounds__(128, 4) void qnet_main(
        const float* __restrict__ embed, const int* __restrict__ rep,
        const float* __restrict__ w1, const float* __restrict__ w2,
        const float* __restrict__ b2, const float* __restrict__ gb,
        float* __restrict__ out, int Bg) {
    // carved LDS: 6x4KB emb ring | 1KB rep8 | 3x512B gb rows | 128B exchange
    __shared__ __align__(16) char smem[27264];
    float*         semb = (float*)smem;                          // [0, 24576)
    unsigned char* rep8 = (unsigned char*)(smem + 24576);        // [24576, 25600)
    float*         gbf  = (float*)(smem + 25600);                // [25600, 27136)
    float*         exch = (float*)(smem + 27136);                // [27136, 27264)

    const int lane = threadIdx.x & 63;
    const int l15  = lane & 15;
    const int g    = lane >> 4;
    const int w    = threadIdx.x >> 6;        // wave role: 0 / 1 (hidden half)
    const int t0   = blockIdx.x * TPB;

    // ---- prologue: rep deltas + Gb row copies into LDS (once per block) ----
    const int bmin = rep[t0 * 16];
    for (int i = threadIdx.x; i < TPB * 16; i += 128) {
        int d = rep[t0 * 16 + i] - bmin;
        rep8[i] = (unsigned char)(d < 255 ? d : 255);
    }
    #pragma unroll
    for (int r = 0; r < 3; ++r) {
        int row = bmin + r; row = row < Bg ? row : Bg - 1;
        gbf[r * H_HID + threadIdx.x] = gb[(size_t)row * H_HID + threadIdx.x];
    }

    // A fragments: this wave's hidden half. lane holds w1[w*64+nt*16+l15][ks*32+g*8+e]
    bf16x8 wfrag[2][4];
    #pragma unroll
    for (int nt = 0; nt < 4; ++nt) {
        const float* wr = w1 + (w * 64 + nt * 16 + l15) * (2 * D_LAT);
        #pragma unroll
        for (int ks = 0; ks < 2; ++ks) {
            f32x4 lo = *reinterpret_cast<const f32x4*>(wr + ks * 32 + g * 8);
            f32x4 hi = *reinterpret_cast<const f32x4*>(wr + ks * 32 + g * 8 + 4);
            wfrag[ks][nt] = pack8(lo, hi);
        }
    }
    f32x4 w2v[4];
    #pragma unroll
    for (int nt = 0; nt < 4; ++nt)
        w2v[nt] = *reinterpret_cast<const f32x4*>(w2 + w * 64 + nt * 16 + g * 4);
    const float b2v = b2[0];

    __syncthreads();   // full drain BEFORE any staging: vm queue empty at stage start

    const unsigned emb_base  = (unsigned)(size_t)(lds_f*)semb;
    const unsigned rep8_base = (unsigned)(size_t)(lds_f*)(float*)(void*)rep8;
    const unsigned exch_base = (unsigned)(size_t)(lds_f*)exch;

    int   cur_idx = -2;
    f32x4 gbv[4];
    #pragma unroll
    for (int nt = 0; nt < 4; ++nt) gbv[nt] = f32x4{0.f, 0.f, 0.f, 0.f};
    float p_prev = 0.f;

    // k-major pre-swizzled global source; LDS dest linear (m173 pattern).
#define STAGE_W0(TT, SLOT) do {                                               \
    const float* s0_ = embed + (size_t)(TT) * 1024 + l15 * 64 + g * 4;        \
    float* d_ = semb + (SLOT) * 1024;                                         \
    gll16(s0_,      d_);                                                      \
    gll16(s0_ + 16, d_ + 256);                                                \
} while (0)
#define STAGE_W1(TT, SLOT) do {                                               \
    const float* s0_ = embed + (size_t)(TT) * 1024 + l15 * 64 + g * 4;        \
    float* d_ = semb + (SLOT) * 1024;                                         \
    gll16(s0_ + 32, d_ + 512);                                                \
    gll16(s0_ + 48, d_ + 768);                                                \
} while (0)

    // gbv refill (LDS cache; rare global fallback), MFMA with C-init, half dot
#define COMPUTE(P, TT)                                                        \
    int rb0 = __shfl(bd, 0, 64), rb15 = __shfl(bd, 15, 64);                   \
    bool uni = (rb0 == rb15);                                                 \
    if (!(uni && rb0 == cur_idx)) {                                           \
        if (__builtin_expect(rb15 >= 3, 0)) {                                 \
            int trow = rep[(size_t)(TT) * 16 + l15];                          \
            const float* gp_ = gb + (size_t)trow * H_HID + w * 64 + g * 4;    \
            gbv[0] = *(const f32x4*)(gp_);      gbv[1] = *(const f32x4*)(gp_ + 16); \
            gbv[2] = *(const f32x4*)(gp_ + 32); gbv[3] = *(const f32x4*)(gp_ + 48); \
        } else {                                                              \
            const float* sp_ = gbf + bd * H_HID + w * 64 + g * 4;             \
            gbv[0] = *(const f32x4*)(sp_);      gbv[1] = *(const f32x4*)(sp_ + 16); \
            gbv[2] = *(const f32x4*)(sp_ + 32); gbv[3] = *(const f32x4*)(sp_ + 48); \
        }                                                                     \
        cur_idx = uni ? rb0 : -1;                                             \
    }                                                                         \
    bf16x8 a0 = pack8(x0, x1), a1 = pack8(x2, x3);                            \
    float P = 0.f;                                                            \
    _Pragma("unroll")                                                         \
    for (int nt = 0; nt < 4; ++nt) {                                          \
        f32x4 z = gbv[nt];                                                    \
        z = MFMA16(wfrag[0][nt], a0, z, 0, 0, 0);                             \
        z = MFMA16(wfrag[1][nt], a1, z, 0, 0, 0);                             \
        _Pragma("unroll")                                                     \
        for (int r = 0; r < 4; ++r) P += fmaxf(z[r], 0.f) * w2v[nt][r];       \
    }                                                                         \
    P += __shfl_xor(P, 16, 64);                                               \
    P += __shfl_xor(P, 32, 64);

#define PH0(CS, TT, I, WN, SS, DOSTAGE, DOSTORE) do {                         \
    asm volatile("s_waitcnt vmcnt(" #WN ")" ::: "memory");                    \
    __builtin_amdgcn_s_barrier();                                             \
    f32x4 x0, x1, x2, x3; int bd; float xv;                                   \
    {                                                                         \
        unsigned ae = emb_base + (unsigned)(CS) * 4096u + g * 512u + l15 * 16u; \
        unsigned ar = rep8_base + (unsigned)(I) * 16u + (unsigned)l15;        \
        unsigned ax = exch_base + (unsigned)(((I) - 1) & 1) * 64u + l15 * 4u; \
        asm volatile(                                                         \
            "ds_read_b128 %0, %6\n\t"                                         \
            "ds_read_b128 %1, %6 offset:256\n\t"                              \
            "ds_read_b128 %2, %6 offset:2048\n\t"                             \
            "ds_read_b128 %3, %6 offset:2304\n\t"                             \
            "ds_read_u8   %4, %7\n\t"                                         \
            "ds_read_b32  %5, %8\n\t"                                         \
            "s_waitcnt lgkmcnt(0)"                                            \
            : "=&v"(x0), "=&v"(x1), "=&v"(x2), "=&v"(x3), "=&v"(bd), "=&v"(xv) \
            : "v"(ae), "v"(ar), "v"(ax) : "memory");                          \
    }                                                                         \
    if (DOSTORE) { if (g == 0) out[((TT) - 1) * 16 + l15] = p_prev + xv + b2v; } \
    if (DOSTAGE) STAGE_W0((TT) + 5, (SS));                                    \
    COMPUTE(p, TT)                                                            \
    p_prev = p;                                                               \
} while (0)

#define PH1(CS, TT, I, WN, SS, DOSTAGE) do {                                  \
    asm volatile("s_waitcnt vmcnt(" #WN ") lgkmcnt(0)" ::: "memory");         \
    __builtin_amdgcn_s_barrier();                                             \
    f32x4 x0, x1, x2, x3; int bd;                                             \
    {                                                                         \
        unsigned ae = emb_base + (unsigned)(CS) * 4096u + g * 512u + l15 * 16u; \
        unsigned ar = rep8_base + (unsigned)(I) * 16u + (unsigned)l15;        \
        asm volatile(                                                         \
            "ds_read_b128 %0, %5\n\t"                                         \
            "ds_read_b128 %1, %5 offset:256\n\t"                              \
            "ds_read_b128 %2, %5 offset:2048\n\t"                             \
            "ds_read_b128 %3, %5 offset:2304\n\t"                             \
            "ds_read_u8   %4, %6\n\t"                                         \
            "s_waitcnt lgkmcnt(0)"                                            \
            : "=&v"(x0), "=&v"(x1), "=&v"(x2), "=&v"(x3), "=&v"(bd)           \
            : "v"(ae), "v"(ar) : "memory");                                   \
    }                                                                         \
    if (DOSTAGE) STAGE_W1((TT) + 5, (SS));                                    \
    COMPUTE(p, TT)                                                            \
    {                                                                         \
        unsigned ax = exch_base + (unsigned)((I) & 1) * 64u + l15 * 4u;       \
        if (g == 0)                                                           \
            asm volatile("ds_write_b32 %0, %1" :: "v"(ax), "v"(p) : "memory"); \
    }                                                                         \
} while (0)

    if (w == 0) {
        STAGE_W0(t0 + 0, 0); STAGE_W0(t0 + 1, 1); STAGE_W0(t0 + 2, 2);
        STAGE_W0(t0 + 3, 3); STAGE_W0(t0 + 4, 4);
        PH0(0, t0 + 0, 0, 8, 5, true, false);
        PH0(1, t0 + 1, 1, 8, 0, true, true);
        PH0(2, t0 + 2, 2, 9, 1, true, true);
        PH0(3, t0 + 3, 3, 10, 2, true, true);
        PH0(4, t0 + 4, 4, 11, 3, true, true);
        {
            int cs = 5, ss = 4;
            for (int i = 5; i <= 58; ++i) {
                PH0(cs, t0 + i, i, 12, ss, true, true);
                ss = cs; cs = (cs == 5) ? 0 : cs + 1;
            }
        }
        PH0(5, t0 + 59, 59, 12, 0, false, true);
        PH0(0, t0 + 60, 60, 10, 0, false, true);
        PH0(1, t0 + 61, 61, 8, 0, false, true);
        PH0(2, t0 + 62, 62, 6, 0, false, true);
        PH0(3, t0 + 63, 63, 4, 0, false, true);
        // final combine for tile t0+63
        __builtin_amdgcn_s_barrier();
        float xv;
        unsigned ax = exch_base + (unsigned)(63 & 1) * 64u + l15 * 4u;
        asm volatile("ds_read_b32 %0, %1\n\ts_waitcnt lgkmcnt(0)"
                     : "=v"(xv) : "v"(ax) : "memory");
        if (g == 0) out[(t0 + 63) * 16 + l15] = p_prev + xv + b2v;
    } else {
        STAGE_W1(t0 + 0, 0); STAGE_W1(t0 + 1, 1); STAGE_W1(t0 + 2, 2);
        STAGE_W1(t0 + 3, 3); STAGE_W1(t0 + 4, 4);
        PH1(0, t0 + 0, 0, 8, 5, true);
        PH1(1, t0 + 1, 1, 8, 0, true);
        PH1(2, t0 + 2, 2, 8, 1, true);
        PH1(3, t0 + 3, 3, 8, 2, true);
        PH1(4, t0 + 4, 4, 8, 3, true);
        {
            int cs = 5, ss = 4;
            for (int i = 5; i <= 58; ++i) {
                PH1(cs, t0 + i, i, 8, ss, true);
                ss = cs; cs = (cs == 5) ? 0 : cs + 1;
            }
        }
        PH1(5, t0 + 59, 59, 8, 0, false);
        PH1(0, t0 + 60, 60, 6, 0, false);
        PH1(1, t0 + 61, 61, 4, 0, false);
        PH1(2, t0 + 62, 62, 2, 0, false);
        PH1(3, t0 + 63, 63, 0, 0, false);
        asm volatile("s_waitcnt lgkmcnt(0)" ::: "memory");
        __builtin_amdgcn_s_barrier();
    }

#undef PH0
#undef PH1
#undef COMPUTE
#undef STAGE_W0
#undef STAGE_W1
}

extern "C" void kernel_launch(void* const* d_in, const int* in_sizes, int n_in,
                              void* d_out, int out_size, void* d_ws, size_t ws_size,
                              hipStream_t stream) {
    const float* embed = (const float*)d_in[0];
    const float* ge    = (const float*)d_in[1];
    const int*   rep   = (const int*)d_in[2];
    const float* w1    = (const float*)d_in[3];
    const float* b1    = (const float*)d_in[4];
    const float* w2    = (const float*)d_in[5];
    const float* b2    = (const float*)d_in[6];
    float* out = (float*)d_out;
    float* gb  = (float*)d_ws;                       // 512*128*4 = 256 KB

    const int N  = in_sizes[0] / D_LAT;
    const int Bg = in_sizes[1] / D_LAT;
    const int num_tiles = N / 16;

    gb_kernel<<<Bg, H_HID, 0, stream>>>(ge, w1, b1, gb);
    // 2048 blocks x 128 thr; 26.6KB LDS -> 6 blocks/CU, ~96KB reads in flight/CU
    qnet_main<<<num_tiles / TPB, 128, 0, stream>>>(embed, rep, w1, w2, b2, gb, out, Bg);
}